// Round 1
// baseline (257.279 us; speedup 1.0000x reference)
//
#include <hip/hip_runtime.h>

// PyramidROIAlign: out[b,n,py,px,c] = bilinear crop from the FPN level
// selected per-box by log2(sqrt(h*w)*sqrt(area)/224).
//
// v2: one 256-thread block (4 waves) per BOX (was: one 64-thread block per
// pool cell). Wave w handles cells w, w+4, ... of the 7x7 grid; lane t
// handles channels [4t,4t+4) via float4. Rationale: the 49 cells of a box
// share bilinear corner rows (<=14 unique rows x ~14 cols x 1KB); putting
// them on ONE CU converts cross-XCD L3/HBM re-fetches into L1/L2 hits, and
// cuts the grid from 98,000 single-wave dispatches to 2,000 blocks
// (8 blocks x 4 waves = 32 waves/CU -> still full occupancy).

__global__ __launch_bounds__(256) void roi_align_kernel(
    const float* __restrict__ boxes,   // (B,N,4) y1,x1,y2,x2
    const float* __restrict__ meta,    // (B,14); meta[4],meta[5] = img H,W
    const float* __restrict__ f2,      // (B,256,256,256)
    const float* __restrict__ f3,      // (B,128,128,256)
    const float* __restrict__ f4,      // (B, 64, 64,256)
    const float* __restrict__ f5,      // (B, 32, 32,256)
    float* __restrict__ out,           // (B,N,7,7,256)
    int N)
{
    const int C = 256;
    int bn = blockIdx.x;                // box index: b*N + n
    int b  = bn / N;

    // ---- per-box scalar setup (computed once per thread, wave-uniform) ----
    float y1 = boxes[bn * 4 + 0];
    float x1 = boxes[bn * 4 + 1];
    float y2 = boxes[bn * 4 + 2];
    float x2 = boxes[bn * 4 + 3];
    float h = y2 - y1;
    float w = x2 - x1;

    // roi_level = clip(4 + round(log2(sqrt(h*w) / (224/sqrt(imgH*imgW)))), 2, 5)
    float area = meta[4] * meta[5];
    float lvl  = log2f(sqrtf(h * w) / (224.0f / sqrtf(area)));
    float rl   = 4.0f + rintf(lvl);          // rintf = half-to-even, matches jnp.round
    rl = fminf(fmaxf(rl, 2.0f), 5.0f);       // -inf (degenerate box) clamps to 2
    int level = (int)rl;

    const float* fm;
    int H;
    if (level == 2)      { fm = f2; H = 256; }
    else if (level == 3) { fm = f3; H = 128; }
    else if (level == 4) { fm = f4; H = 64;  }
    else                 { fm = f5; H = 32;  }
    int W = H;

    // step sizes (match reference fp32 op order: (h*(H-1))/6)
    float sy = (h * (float)(H - 1)) / 6.0f;
    float sx = (w * (float)(W - 1)) / 6.0f;
    float ybase = y1 * (float)(H - 1);
    float xbase = x1 * (float)(W - 1);

    const float* fb = fm + (size_t)b * H * W * C;
    float* ob = out + (size_t)bn * 49 * C;

    int wave = threadIdx.x >> 6;         // 0..3
    int lane = threadIdx.x & 63;         // 0..63 -> 4 channels each

    for (int pc = wave; pc < 49; pc += 4) {
        int py = pc / 7;
        int px = pc - py * 7;

        float ys = ybase + (float)py * sy;
        float xs = xbase + (float)px * sx;
        float y0f = floorf(ys);
        float x0f = floorf(xs);
        int y0 = min(max((int)y0f, 0), H - 1);
        int yi = min(y0 + 1, H - 1);
        int x0 = min(max((int)x0f, 0), W - 1);
        int xi = min(x0 + 1, W - 1);
        float fy = ys - y0f;
        float fx = xs - x0f;

        const float4* ptl = (const float4*)(fb + ((size_t)y0 * W + x0) * C);
        const float4* ptr = (const float4*)(fb + ((size_t)y0 * W + xi) * C);
        const float4* pbl = (const float4*)(fb + ((size_t)yi * W + x0) * C);
        const float4* pbr = (const float4*)(fb + ((size_t)yi * W + xi) * C);

        float4 tl = ptl[lane];
        float4 tr = ptr[lane];
        float4 bl = pbl[lane];
        float4 br = pbr[lane];

        float4 o;
        {
            float top = tl.x + (tr.x - tl.x) * fx;
            float bot = bl.x + (br.x - bl.x) * fx;
            o.x = top + (bot - top) * fy;
        }
        {
            float top = tl.y + (tr.y - tl.y) * fx;
            float bot = bl.y + (br.y - bl.y) * fx;
            o.y = top + (bot - top) * fy;
        }
        {
            float top = tl.z + (tr.z - tl.z) * fx;
            float bot = bl.z + (br.z - bl.z) * fx;
            o.z = top + (bot - top) * fy;
        }
        {
            float top = tl.w + (tr.w - tl.w) * fx;
            float bot = bl.w + (br.w - bl.w) * fx;
            o.w = top + (bot - top) * fy;
        }

        ((float4*)(ob + (size_t)pc * C))[lane] = o;
    }
}

extern "C" void kernel_launch(void* const* d_in, const int* in_sizes, int n_in,
                              void* d_out, int out_size, void* d_ws, size_t ws_size,
                              hipStream_t stream) {
    const float* boxes = (const float*)d_in[0];
    const float* meta  = (const float*)d_in[1];
    const float* f2    = (const float*)d_in[2];
    const float* f3    = (const float*)d_in[3];
    const float* f4    = (const float*)d_in[4];
    const float* f5    = (const float*)d_in[5];
    float* out = (float*)d_out;

    int B = in_sizes[1] / 14;            // image_meta is (B,14)
    int N = in_sizes[0] / (4 * B);       // boxes is (B,N,4)

    int grid = B * N;                    // one 4-wave block per box
    roi_align_kernel<<<grid, 256, 0, stream>>>(boxes, meta, f2, f3, f4, f5, out, N);
}

// Round 2
// 245.511 us; speedup vs baseline: 1.0479x; 1.0479x over previous
//
#include <hip/hip_runtime.h>

// PyramidROIAlign: out[b,n,py,px,c] = bilinear crop from the FPN level
// selected per-box by log2(sqrt(h*w)*sqrt(area)/224).
//
// v3: one 448-thread block (7 waves) per (box, pool-row). Wave px handles
// cell (py,px); lane t handles channels [4t,4t+4) via float4.
// Rationale: v1 (1 wave/cell, 98k blocks) had full TLP but scattered the
// row-sharing cells across XCDs; v2 (4 waves/box loop) had locality but
// only 8k waves -> latency-bound serial loop, regressed. v3 keeps the full
// 98k-wave TLP (no per-wave loop, 4 independent loads, one store) AND puts
// the 7 cells of a pool row -- which read the same two feature rows y0,yi
// with overlapping corner columns -- on one CU so repeats hit L1/L2.

__global__ __launch_bounds__(448) void roi_align_kernel(
    const float* __restrict__ boxes,   // (B,N,4) y1,x1,y2,x2
    const float* __restrict__ meta,    // (B,14); meta[4],meta[5] = img H,W
    const float* __restrict__ f2,      // (B,256,256,256)
    const float* __restrict__ f3,      // (B,128,128,256)
    const float* __restrict__ f4,      // (B, 64, 64,256)
    const float* __restrict__ f5,      // (B, 32, 32,256)
    float* __restrict__ out,           // (B,N,7,7,256)
    int N)
{
    const int C = 256;
    int bid = blockIdx.x;               // bn*7 + py
    int bn  = bid / 7;
    int py  = bid - bn * 7;
    int b   = bn / N;
    int px  = threadIdx.x >> 6;         // wave id 0..6 = pool column
    int lane = threadIdx.x & 63;        // 4 channels each

    // ---- per-box scalar setup (wave-uniform) ----
    float y1 = boxes[bn * 4 + 0];
    float x1 = boxes[bn * 4 + 1];
    float y2 = boxes[bn * 4 + 2];
    float x2 = boxes[bn * 4 + 3];
    float h = y2 - y1;
    float w = x2 - x1;

    // roi_level = clip(4 + round(log2(sqrt(h*w) / (224/sqrt(imgH*imgW)))), 2, 5)
    float area = meta[4] * meta[5];
    float lvl  = log2f(sqrtf(h * w) / (224.0f / sqrtf(area)));
    float rl   = 4.0f + rintf(lvl);          // rintf = half-to-even, matches jnp.round
    rl = fminf(fmaxf(rl, 2.0f), 5.0f);       // -inf (degenerate box) clamps to 2
    int level = (int)rl;

    const float* fm;
    int H;
    if (level == 2)      { fm = f2; H = 256; }
    else if (level == 3) { fm = f3; H = 128; }
    else if (level == 4) { fm = f4; H = 64;  }
    else                 { fm = f5; H = 32;  }
    int W = H;

    // ---- sample coordinates (match reference fp32 op order) ----
    float sy = (h * (float)(H - 1)) / 6.0f;
    float sx = (w * (float)(W - 1)) / 6.0f;
    float ys = y1 * (float)(H - 1) + (float)py * sy;
    float xs = x1 * (float)(W - 1) + (float)px * sx;
    float y0f = floorf(ys);
    float x0f = floorf(xs);
    int y0 = min(max((int)y0f, 0), H - 1);
    int yi = min(y0 + 1, H - 1);
    int x0 = min(max((int)x0f, 0), W - 1);
    int xi = min(x0 + 1, W - 1);
    float fy = ys - y0f;
    float fx = xs - x0f;

    size_t base = (size_t)b * H * W * C;
    const float4* ptl = (const float4*)(fm + base + ((size_t)y0 * W + x0) * C);
    const float4* ptr = (const float4*)(fm + base + ((size_t)y0 * W + xi) * C);
    const float4* pbl = (const float4*)(fm + base + ((size_t)yi * W + x0) * C);
    const float4* pbr = (const float4*)(fm + base + ((size_t)yi * W + xi) * C);

    float4 tl = ptl[lane];
    float4 tr = ptr[lane];
    float4 bl = pbl[lane];
    float4 br = pbr[lane];

    float4 o;
    {
        float top = tl.x + (tr.x - tl.x) * fx;
        float bot = bl.x + (br.x - bl.x) * fx;
        o.x = top + (bot - top) * fy;
    }
    {
        float top = tl.y + (tr.y - tl.y) * fx;
        float bot = bl.y + (br.y - bl.y) * fx;
        o.y = top + (bot - top) * fy;
    }
    {
        float top = tl.z + (tr.z - tl.z) * fx;
        float bot = bl.z + (br.z - bl.z) * fx;
        o.z = top + (bot - top) * fy;
    }
    {
        float top = tl.w + (tr.w - tl.w) * fx;
        float bot = bl.w + (br.w - bl.w) * fx;
        o.w = top + (bot - top) * fy;
    }

    float4* po = (float4*)(out + ((size_t)bn * 49 + (size_t)py * 7 + px) * C);
    po[lane] = o;
}

extern "C" void kernel_launch(void* const* d_in, const int* in_sizes, int n_in,
                              void* d_out, int out_size, void* d_ws, size_t ws_size,
                              hipStream_t stream) {
    const float* boxes = (const float*)d_in[0];
    const float* meta  = (const float*)d_in[1];
    const float* f2    = (const float*)d_in[2];
    const float* f3    = (const float*)d_in[3];
    const float* f4    = (const float*)d_in[4];
    const float* f5    = (const float*)d_in[5];
    float* out = (float*)d_out;

    int B = in_sizes[1] / 14;            // image_meta is (B,14)
    int N = in_sizes[0] / (4 * B);       // boxes is (B,N,4)

    int grid = B * N * 7;                // one 7-wave block per (box, pool row)
    roi_align_kernel<<<grid, 448, 0, stream>>>(boxes, meta, f2, f3, f4, f5, out, N);
}